// Round 4
// baseline (229.471 us; speedup 1.0000x reference)
//
#include <hip/hip_runtime.h>
#include <hip/hip_bf16.h>
#include <math.h>

// PairwiseCosineSimilarity: C[n][m] = <x1[n], x2[m]> / (max(||x1[n]||,eps)*max(||x2[m]||,eps))
// Plan: normalize rows to bf16 in d_ws, then bf16 MFMA GEMM C = An * Bn^T.
// 128x128 tile, BK=64, 4 waves (2x2), 4x4 16x16x32 fragments per wave,
// global_load_lds width=16 staging (linear LDS), XOR-swizzled k-groups
// (pre-swizzled global source + swizzled ds_read) to kill bank conflicts.

typedef __bf16 bf16x8 __attribute__((ext_vector_type(8)));
typedef float  f32x4  __attribute__((ext_vector_type(4)));

#define LDSP(x) ((__attribute__((address_space(3))) void*)(x))
#define GLBP(x) ((const __attribute__((address_space(1))) void*)(x))

#define BM 128
#define BN 128
#define BK 64
#define EPS_CS 1e-8f

// ---------------- fast path ----------------

// One block per row, D == 1024, 256 threads * float4.
__global__ __launch_bounds__(256) void nrm_bf16_1024(const float* __restrict__ in,
                                                     __bf16* __restrict__ out) {
    const int row = blockIdx.x;
    const int t = threadIdx.x;
    const float4 v = reinterpret_cast<const float4*>(in + (size_t)row * 1024)[t];
    float ss = v.x * v.x + v.y * v.y + v.z * v.z + v.w * v.w;
#pragma unroll
    for (int off = 32; off > 0; off >>= 1) ss += __shfl_down(ss, off, 64);
    __shared__ float red[4];
    const int lane = t & 63, wid = t >> 6;
    if (lane == 0) red[wid] = ss;
    __syncthreads();
    const float tot = red[0] + red[1] + red[2] + red[3];
    const float rn = 1.0f / fmaxf(sqrtf(tot), EPS_CS);
    const __bf16 b0 = (__bf16)(v.x * rn);
    const __bf16 b1 = (__bf16)(v.y * rn);
    const __bf16 b2 = (__bf16)(v.z * rn);
    const __bf16 b3 = (__bf16)(v.w * rn);
    ushort4 pk;
    pk.x = __builtin_bit_cast(unsigned short, b0);
    pk.y = __builtin_bit_cast(unsigned short, b1);
    pk.z = __builtin_bit_cast(unsigned short, b2);
    pk.w = __builtin_bit_cast(unsigned short, b3);
    reinterpret_cast<ushort4*>(out + (size_t)row * 1024)[t] = pk;
}

// C[NR][NC] = A[NR][D] * B[NC][D]^T   (A,B bf16 row-major, C f32 row-major)
// NR,NC multiples of 128; D multiple of 64. Grid = (NR/128)*(NC/128), block=256.
__global__ __launch_bounds__(256) void gemm_nt_bf16(const __bf16* __restrict__ A,
                                                    const __bf16* __restrict__ B,
                                                    float* __restrict__ C,
                                                    int NR, int NC, int D) {
    __shared__ __bf16 As[BM * BK];  // 16 KB
    __shared__ __bf16 Bs[BN * BK];  // 16 KB

    const int t    = threadIdx.x;
    const int lane = t & 63;
    const int wid  = t >> 6;
    const int wr   = wid >> 1;               // wave row  0..1 (64-row strips)
    const int wc   = wid & 1;                // wave col  0..1 (64-col strips)
    const int fr   = lane & 15;              // fragment row/col within 16
    const int fk   = (lane >> 4) << 3;       // k offset 0,8,16,24
    const int xk   = fr & 7;                 // LDS read XOR key (row&7)

    // XCD-aware bijective swizzle (grid is a multiple of 8 here: 4096)
    const int nwg = gridDim.x;
    int swz = blockIdx.x;
    if ((nwg & 7) == 0) swz = (swz & 7) * (nwg >> 3) + (swz >> 3);
    const int ntn  = NC / BN;
    const int brow = swz / ntn;
    const int bcol = swz % ntn;

    // staging decomposition: slot s = i*256 + t covers LDS elements [s*8, s*8+8)
    //   row(s) = s>>3 = i*32 + (t>>3), lds k-group = s&7 = t&7
    //   global k-group = (t&7) ^ (row&7)  -> pre-swizzled source, linear LDS dest
    const int srow  = t >> 3;                                   // 0..31
    const int sgrp  = ((t & 7) ^ ((t >> 3) & 7)) << 3;          // swizzled k element offset
    const size_t a_base = (size_t)(brow * BM) * D;
    const size_t b_base = (size_t)(bcol * BN) * D;

    f32x4 acc[4][4];
#pragma unroll
    for (int m = 0; m < 4; ++m)
#pragma unroll
        for (int n = 0; n < 4; ++n)
            acc[m][n] = (f32x4){0.f, 0.f, 0.f, 0.f};

    for (int k0 = 0; k0 < D; k0 += BK) {
        // ---- stage A,B tiles (128x64 bf16 each) via global_load_lds x16B ----
#pragma unroll
        for (int i = 0; i < 4; ++i) {
            const int r = i * 32 + srow;
            __builtin_amdgcn_global_load_lds(
                GLBP(A + a_base + (size_t)r * D + k0 + sgrp),
                LDSP(&As[(i * 256 + t) * 8]), 16, 0, 0);
        }
#pragma unroll
        for (int i = 0; i < 4; ++i) {
            const int r = i * 32 + srow;
            __builtin_amdgcn_global_load_lds(
                GLBP(B + b_base + (size_t)r * D + k0 + sgrp),
                LDSP(&Bs[(i * 256 + t) * 8]), 16, 0, 0);
        }
        __syncthreads();   // compiler drains vmcnt(0) before s_barrier

        // ---- compute: 2 k-slices of 32, 16 MFMA each ----
#pragma unroll
        for (int kk = 0; kk < BK; kk += 32) {
            bf16x8 af[4], bf[4];
#pragma unroll
            for (int m = 0; m < 4; ++m) {
                const int row = wr * 64 + m * 16 + fr;
                const int g   = (((kk + fk) >> 3) ^ xk) << 3;
                af[m] = *reinterpret_cast<const bf16x8*>(&As[row * BK + g]);
            }
#pragma unroll
            for (int n = 0; n < 4; ++n) {
                const int row = wc * 64 + n * 16 + fr;
                const int g   = (((kk + fk) >> 3) ^ xk) << 3;
                bf[n] = *reinterpret_cast<const bf16x8*>(&Bs[row * BK + g]);
            }
#pragma unroll
            for (int m = 0; m < 4; ++m)
#pragma unroll
                for (int n = 0; n < 4; ++n)
                    acc[m][n] = __builtin_amdgcn_mfma_f32_16x16x32_bf16(af[m], bf[n], acc[m][n], 0, 0, 0);
        }
        __syncthreads();
    }

    // ---- epilogue: D[row][col], col = lane&15, row = (lane>>4)*4 + reg ----
    const int crow0 = brow * BM + wr * 64;
    const int ccol0 = bcol * BN + wc * 64;
    const int rr    = (lane >> 4) * 4;
#pragma unroll
    for (int m = 0; m < 4; ++m) {
#pragma unroll
        for (int r = 0; r < 4; ++r) {
            const size_t rowoff = (size_t)(crow0 + m * 16 + rr + r) * NC;
#pragma unroll
            for (int n = 0; n < 4; ++n)
                C[rowoff + ccol0 + n * 16 + fr] = acc[m][n][r];
        }
    }
}

// ---------------- fallback path (ws too small / odd shapes) ----------------

__global__ __launch_bounds__(256) void rnorm_rows(const float* __restrict__ in,
                                                  float* __restrict__ rn, int D) {
    const int row = blockIdx.x;
    float ss = 0.f;
    for (int c = threadIdx.x; c < D; c += 256) {
        const float v = in[(size_t)row * D + c];
        ss += v * v;
    }
#pragma unroll
    for (int off = 32; off > 0; off >>= 1) ss += __shfl_down(ss, off, 64);
    __shared__ float red[4];
    if ((threadIdx.x & 63) == 0) red[threadIdx.x >> 6] = ss;
    __syncthreads();
    if (threadIdx.x == 0) {
        const float tot = red[0] + red[1] + red[2] + red[3];
        rn[row] = 1.0f / fmaxf(sqrtf(tot), EPS_CS);
    }
}

__global__ __launch_bounds__(256) void gemm_f32_fallback(const float* __restrict__ x1,
                                                         const float* __restrict__ x2,
                                                         const float* __restrict__ rn1,
                                                         const float* __restrict__ rn2,
                                                         float* __restrict__ C,
                                                         int NR, int NC, int D) {
    __shared__ float a[16][17], b[16][17];
    const int tx = threadIdx.x & 15, ty = threadIdx.x >> 4;
    const int row = blockIdx.y * 16 + ty;
    const int colb = blockIdx.x * 16;
    float acc = 0.f;
    for (int k0 = 0; k0 < D; k0 += 16) {
        a[ty][tx] = (row < NR && k0 + tx < D) ? x1[(size_t)row * D + k0 + tx] : 0.f;
        b[ty][tx] = (colb + ty < NC && k0 + tx < D) ? x2[(size_t)(colb + ty) * D + k0 + tx] : 0.f;
        __syncthreads();
#pragma unroll
        for (int k = 0; k < 16; ++k) acc += a[ty][k] * b[tx][k];
        __syncthreads();
    }
    if (row < NR && colb + tx < NC)
        C[(size_t)row * NC + colb + tx] = acc * rn1[row] * rn2[colb + tx];
}

// ---------------- launch ----------------

extern "C" void kernel_launch(void* const* d_in, const int* in_sizes, int n_in,
                              void* d_out, int out_size, void* d_ws, size_t ws_size,
                              hipStream_t stream) {
    const float* x1 = (const float*)d_in[0];
    const float* x2 = (const float*)d_in[1];
    float* C = (float*)d_out;

    const int D  = 1024;
    const int NR = in_sizes[0] / D;
    const int NC = in_sizes[1] / D;

    const size_t need = ((size_t)NR + (size_t)NC) * (size_t)D * sizeof(__bf16);
    const bool fast = (in_sizes[0] % D == 0) && (in_sizes[1] % D == 0) &&
                      (NR % BM == 0) && (NC % BN == 0) && (ws_size >= need);

    if (fast) {
        __bf16* An = (__bf16*)d_ws;
        __bf16* Bn = An + (size_t)NR * D;
        nrm_bf16_1024<<<NR, 256, 0, stream>>>(x1, An);
        nrm_bf16_1024<<<NC, 256, 0, stream>>>(x2, Bn);
        const int grid = (NR / BM) * (NC / BN);
        gemm_nt_bf16<<<grid, 256, 0, stream>>>(An, Bn, C, NR, NC, D);
    } else {
        float* rn1 = (float*)d_ws;
        float* rn2 = rn1 + NR;
        rnorm_rows<<<NR, 256, 0, stream>>>(x1, rn1, D);
        rnorm_rows<<<NC, 256, 0, stream>>>(x2, rn2, D);
        dim3 g((NC + 15) / 16, (NR + 15) / 16);
        gemm_f32_fallback<<<g, 256, 0, stream>>>(x1, x2, rn1, rn2, C, NR, NC, D);
    }
}

// Round 5
// 185.588 us; speedup vs baseline: 1.2365x; 1.2365x over previous
//
#include <hip/hip_runtime.h>
#include <hip/hip_bf16.h>
#include <math.h>

// PairwiseCosineSimilarity: C[n][m] = <x1[n],x2[m]> / (max(||x1||,eps)*max(||x2||,eps))
// Round 5: normalize rows -> bf16, then 256x256-tile MFMA GEMM with a
// 4-phase/K-tile software pipeline: raw s_barrier + counted vmcnt (never
// drains to 0 in the main loop), setprio(1) around MFMA clusters,
// zero-conflict XOR-swizzled LDS (pre-swizzled global source, swizzled read),
// XCD-aware block swizzle.

typedef __bf16 bf16x8 __attribute__((ext_vector_type(8)));
typedef float  f32x4  __attribute__((ext_vector_type(4)));

#define LDSP(x) ((__attribute__((address_space(3))) void*)(x))
#define GLBP(x) ((const __attribute__((address_space(1))) void*)(x))

#define BM 256
#define BN 256
#define BK 64
#define EPS_CS 1e-8f

// ---------------- normalize: one block per row, D == 1024 ----------------

__global__ __launch_bounds__(256) void nrm_bf16_1024(const float* __restrict__ in,
                                                     __bf16* __restrict__ out) {
    const int row = blockIdx.x;
    const int t = threadIdx.x;
    const float4 v = reinterpret_cast<const float4*>(in + (size_t)row * 1024)[t];
    float ss = v.x * v.x + v.y * v.y + v.z * v.z + v.w * v.w;
#pragma unroll
    for (int off = 32; off > 0; off >>= 1) ss += __shfl_down(ss, off, 64);
    __shared__ float red[4];
    const int lane = t & 63, wid = t >> 6;
    if (lane == 0) red[wid] = ss;
    __syncthreads();
    const float tot = red[0] + red[1] + red[2] + red[3];
    const float rn = 1.0f / fmaxf(sqrtf(tot), EPS_CS);
    ushort4 pk;
    pk.x = __builtin_bit_cast(unsigned short, (__bf16)(v.x * rn));
    pk.y = __builtin_bit_cast(unsigned short, (__bf16)(v.y * rn));
    pk.z = __builtin_bit_cast(unsigned short, (__bf16)(v.z * rn));
    pk.w = __builtin_bit_cast(unsigned short, (__bf16)(v.w * rn));
    reinterpret_cast<ushort4*>(out + (size_t)row * 1024)[t] = pk;
}

// ---------------- 256x256 pipelined MFMA GEMM:  C = A * B^T ----------------
// A[NR][D], B[NC][D] bf16 row-major; C[NR][NC] f32. NR,NC % 256 == 0, D % 64 == 0.
// Grid = (NR/256)*(NC/256), block = 512 (8 waves, 2x4). Per wave: 128x64 output,
// acc[8][4] f32x4. LDS: 2 x (A 256x64 + B 256x64) bf16 = 128 KB.

__global__ __launch_bounds__(512, 2) void gemm_nt_bf16_256(const __bf16* __restrict__ A,
                                                           const __bf16* __restrict__ B,
                                                           float* __restrict__ C,
                                                           int NC, int D) {
    __shared__ __bf16 As[2][BM * BK];   // 2 x 32 KB
    __shared__ __bf16 Bs[2][BN * BK];   // 2 x 32 KB

    const int t    = threadIdx.x;
    const int lane = t & 63;
    const int wid  = t >> 6;            // 0..7
    const int wm   = wid >> 2;          // 0..1  (128-row strip)
    const int wn   = wid & 3;           // 0..3  (64-col strip)
    const int fr   = lane & 15;         // fragment row/col
    const int fq   = lane >> 4;         // 0..3  (k sub-group)
    const int xk   = fr & 7;            // read XOR key == (row & 7)
    const int g0   = fq ^ xk;           // kh=0 physical 16B-group
    const int g1   = (4 + fq) ^ xk;     // kh=1 physical 16B-group

    // XCD-aware bijective block swizzle (grid % 8 == 0 on the fast path)
    const int nwg = gridDim.x;
    int swz = blockIdx.x;
    if ((nwg & 7) == 0) swz = (swz & 7) * (nwg >> 3) + (swz >> 3);
    const int ntn  = NC / BN;
    const int brow = (swz / ntn) * BM;
    const int bcol = (swz % ntn) * BN;

    // staging: thread t covers LDS elements [t*8, t*8+8) of a 64-row slab.
    // LDS row-in-slab = t>>3, physical group = t&7; source k-group is
    // pre-swizzled: (t&7) ^ (row&7)  (inverse of the read XOR).
    const int srow = t >> 3;                         // 0..63
    const int sg8  = ((t & 7) ^ (srow & 7)) << 3;    // swizzled k element offset
    const __bf16* aSrc = A + (size_t)(brow + srow) * D + sg8;
    const __bf16* bSrc = B + (size_t)(bcol + srow) * D + sg8;
    const int ldsOff = t * 8;

    auto stageA = [&](int buf, int slab, int k) {
        __builtin_amdgcn_global_load_lds(GLBP(aSrc + (size_t)slab * 64 * D + k),
                                         LDSP(&As[buf][slab * 4096 + ldsOff]), 16, 0, 0);
    };
    auto stageB = [&](int buf, int slab, int k) {
        __builtin_amdgcn_global_load_lds(GLBP(bSrc + (size_t)slab * 64 * D + k),
                                         LDSP(&Bs[buf][slab * 4096 + ldsOff]), 16, 0, 0);
    };
    auto ldA = [&](int buf, int mh, int m, int g) {
        const int row = wm * 128 + mh * 64 + m * 16 + fr;
        return *reinterpret_cast<const bf16x8*>(&As[buf][row * 64 + g * 8]);
    };
    auto ldB = [&](int buf, int n, int g) {
        const int row = wn * 64 + n * 16 + fr;
        return *reinterpret_cast<const bf16x8*>(&Bs[buf][row * 64 + g * 8]);
    };

    f32x4 acc[8][4];
#pragma unroll
    for (int i = 0; i < 8; ++i)
#pragma unroll
        for (int n = 0; n < 4; ++n)
            acc[i][n] = (f32x4){0.f, 0.f, 0.f, 0.f};

    // ---- prologue: stage K-tile 0 into buf 0, drain once ----
#pragma unroll
    for (int s = 0; s < 4; ++s) stageB(0, s, 0);
#pragma unroll
    for (int s = 0; s < 4; ++s) stageA(0, s, 0);
    asm volatile("s_waitcnt vmcnt(0)" ::: "memory");
    __builtin_amdgcn_s_barrier();

    const int NT = D / BK;
    int cur = 0;
    for (int kt = 0; kt < NT; ++kt) {
        const int nb = cur ^ 1;
        const int kn = (kt + 1 < NT ? kt + 1 : 0) * BK;  // last iter re-stages tile 0
                                                         // (never read; keeps vmcnt counts uniform)
        bf16x8 a[4], b[4];

        // ======== phase 1: kh=0, mh=0 ========
#pragma unroll
        for (int n = 0; n < 4; ++n) b[n] = ldB(cur, n, g0);
#pragma unroll
        for (int m = 0; m < 4; ++m) a[m] = ldA(cur, 0, m, g0);
        stageB(nb, 0, kn); stageB(nb, 1, kn);
        __builtin_amdgcn_s_barrier();
        __builtin_amdgcn_s_setprio(1);
#pragma unroll
        for (int m = 0; m < 4; ++m)
#pragma unroll
            for (int n = 0; n < 4; ++n)
                acc[m][n] = __builtin_amdgcn_mfma_f32_16x16x32_bf16(a[m], b[n], acc[m][n], 0, 0, 0);
        __builtin_amdgcn_s_setprio(0);
        // wait prev-iter's A1,A3 (oldest 2); leave this phase's 2 stages in flight
        asm volatile("s_waitcnt vmcnt(2)" ::: "memory");
        __builtin_amdgcn_s_barrier();

        // ======== phase 2: kh=0, mh=1 (reuse b) ========
#pragma unroll
        for (int m = 0; m < 4; ++m) a[m] = ldA(cur, 1, m, g0);
        stageB(nb, 2, kn); stageB(nb, 3, kn);
        __builtin_amdgcn_s_barrier();
        __builtin_amdgcn_s_setprio(1);
#pragma unroll
        for (int m = 0; m < 4; ++m)
#pragma unroll
            for (int n = 0; n < 4; ++n)
                acc[4 + m][n] = __builtin_amdgcn_mfma_f32_16x16x32_bf16(a[m], b[n], acc[4 + m][n], 0, 0, 0);
        __builtin_amdgcn_s_setprio(0);
        __builtin_amdgcn_s_barrier();

        // ======== phase 3: kh=1, mh=0 ========
#pragma unroll
        for (int n = 0; n < 4; ++n) b[n] = ldB(cur, n, g1);
#pragma unroll
        for (int m = 0; m < 4; ++m) a[m] = ldA(cur, 0, m, g1);
        stageA(nb, 0, kn); stageA(nb, 2, kn);
        __builtin_amdgcn_s_barrier();
        __builtin_amdgcn_s_setprio(1);
#pragma unroll
        for (int m = 0; m < 4; ++m)
#pragma unroll
            for (int n = 0; n < 4; ++n)
                acc[m][n] = __builtin_amdgcn_mfma_f32_16x16x32_bf16(a[m], b[n], acc[m][n], 0, 0, 0);
        __builtin_amdgcn_s_setprio(0);
        __builtin_amdgcn_s_barrier();

        // ======== phase 4: kh=1, mh=1 ========
#pragma unroll
        for (int m = 0; m < 4; ++m) a[m] = ldA(cur, 1, m, g1);
        stageA(nb, 1, kn); stageA(nb, 3, kn);
        __builtin_amdgcn_s_barrier();
        __builtin_amdgcn_s_setprio(1);
#pragma unroll
        for (int m = 0; m < 4; ++m)
#pragma unroll
            for (int n = 0; n < 4; ++n)
                acc[4 + m][n] = __builtin_amdgcn_mfma_f32_16x16x32_bf16(a[m], b[n], acc[4 + m][n], 0, 0, 0);
        __builtin_amdgcn_s_setprio(0);
        // wait next tile's B0-3,A0,A2 (oldest 6); leave A1,A3 in flight
        asm volatile("s_waitcnt vmcnt(2)" ::: "memory");
        __builtin_amdgcn_s_barrier();

        cur = nb;
    }

    // ---- epilogue: D[row][col], col = lane&15, row = (lane>>4)*4 + reg ----
    const int crow0 = brow + wm * 128;
    const int ccol0 = bcol + wn * 64;
    const int rr    = fq * 4;
#pragma unroll
    for (int mh = 0; mh < 2; ++mh) {
#pragma unroll
        for (int m = 0; m < 4; ++m) {
#pragma unroll
            for (int r = 0; r < 4; ++r) {
                const size_t rowoff = (size_t)(crow0 + mh * 64 + m * 16 + rr + r) * NC;
#pragma unroll
                for (int n = 0; n < 4; ++n)
                    C[rowoff + ccol0 + n * 16 + fr] = acc[mh * 4 + m][n][r];
            }
        }
    }
}

// ---------------- fallback path (odd shapes / tiny ws) ----------------

__global__ __launch_bounds__(256) void rnorm_rows(const float* __restrict__ in,
                                                  float* __restrict__ rn, int D) {
    const int row = blockIdx.x;
    float ss = 0.f;
    for (int c = threadIdx.x; c < D; c += 256) {
        const float v = in[(size_t)row * D + c];
        ss += v * v;
    }
#pragma unroll
    for (int off = 32; off > 0; off >>= 1) ss += __shfl_down(ss, off, 64);
    __shared__ float red[4];
    if ((threadIdx.x & 63) == 0) red[threadIdx.x >> 6] = ss;
    __syncthreads();
    if (threadIdx.x == 0) {
        const float tot = red[0] + red[1] + red[2] + red[3];
        rn[row] = 1.0f / fmaxf(sqrtf(tot), EPS_CS);
    }
}

__global__ __launch_bounds__(256) void gemm_f32_fallback(const float* __restrict__ x1,
                                                         const float* __restrict__ x2,
                                                         const float* __restrict__ rn1,
                                                         const float* __restrict__ rn2,
                                                         float* __restrict__ C,
                                                         int NR, int NC, int D) {
    __shared__ float a[16][17], b[16][17];
    const int tx = threadIdx.x & 15, ty = threadIdx.x >> 4;
    const int row = blockIdx.y * 16 + ty;
    const int colb = blockIdx.x * 16;
    float acc = 0.f;
    for (int k0 = 0; k0 < D; k0 += 16) {
        a[ty][tx] = (row < NR && k0 + tx < D) ? x1[(size_t)row * D + k0 + tx] : 0.f;
        b[ty][tx] = (colb + ty < NC && k0 + tx < D) ? x2[(size_t)(colb + ty) * D + k0 + tx] : 0.f;
        __syncthreads();
#pragma unroll
        for (int k = 0; k < 16; ++k) acc += a[ty][k] * b[tx][k];
        __syncthreads();
    }
    if (row < NR && colb + tx < NC)
        C[(size_t)row * NC + colb + tx] = acc * rn1[row] * rn2[colb + tx];
}

// ---------------- launch ----------------

extern "C" void kernel_launch(void* const* d_in, const int* in_sizes, int n_in,
                              void* d_out, int out_size, void* d_ws, size_t ws_size,
                              hipStream_t stream) {
    const float* x1 = (const float*)d_in[0];
    const float* x2 = (const float*)d_in[1];
    float* C = (float*)d_out;

    const int D  = 1024;
    const int NR = in_sizes[0] / D;
    const int NC = in_sizes[1] / D;

    const size_t need = ((size_t)NR + (size_t)NC) * (size_t)D * sizeof(__bf16);
    const bool fast = (in_sizes[0] % D == 0) && (in_sizes[1] % D == 0) &&
                      (NR % BM == 0) && (NC % BN == 0) && (ws_size >= need);

    if (fast) {
        __bf16* An = (__bf16*)d_ws;
        __bf16* Bn = An + (size_t)NR * D;
        nrm_bf16_1024<<<NR, 256, 0, stream>>>(x1, An);
        nrm_bf16_1024<<<NC, 256, 0, stream>>>(x2, Bn);
        const int grid = (NR / BM) * (NC / BN);
        gemm_nt_bf16_256<<<grid, 512, 0, stream>>>(An, Bn, C, NC, D);
    } else {
        float* rn1 = (float*)d_ws;
        float* rn2 = rn1 + NR;
        rnorm_rows<<<NR, 256, 0, stream>>>(x1, rn1, D);
        rnorm_rows<<<NC, 256, 0, stream>>>(x2, rn2, D);
        dim3 g((NC + 15) / 16, (NR + 15) / 16);
        gemm_f32_fallback<<<g, 256, 0, stream>>>(x1, x2, rn1, rn2, C, NR, NC, D);
    }
}